// Round 5
// baseline (131.668 us; speedup 1.0000x reference)
//
#include <hip/hip_runtime.h>
#include <hip/hip_bf16.h>
#include <cstdint>

#define B_SIZE 4096
#define TWO_B  8192
#define DIM    512           // row length; fp8 => 512 bytes per row
#define NBLK   1056          // blocks: (I,J), I in [0,32), J in [2I,64)
// exp(x/t) = exp2(x * log2(e)/t), t = 0.5
#define EXP_SCALE 2.8853900817779268f

typedef __attribute__((ext_vector_type(4))) float f32x4;

// raw waitcnt: vmcnt(n) with lgkmcnt/expcnt unconstrained (gfx9 encoding)
#define WAITVM(n) __builtin_amdgcn_s_waitcnt(0xF70 | (n))
#define BARRIER() __builtin_amdgcn_s_barrier()

// ---------- helpers ----------
__device__ __forceinline__ void async16(const void* g, void* l) {
    __builtin_amdgcn_global_load_lds(
        (const __attribute__((address_space(1))) unsigned int*)g,
        (__attribute__((address_space(3))) unsigned int*)l,
        16, 0, 0);
}

// ---------- kernel 1: L2-normalize rows -> fp8 reps, fp32 positives ----------
__global__ __launch_bounds__(256) void norm_pos_kernel(
    const float* __restrict__ emb_i, const float* __restrict__ emb_j,
    unsigned char* __restrict__ reps, float* __restrict__ pos,
    float* __restrict__ out)
{
    __shared__ float sc[3][4];
    int b = blockIdx.x, t = threadIdx.x;
    if (b == 0 && t == 0) out[0] = 0.0f;       // loss kernel accumulates atomically

    const float2* ri = (const float2*)(emb_i + (size_t)b * DIM);
    const float2* rj = (const float2*)(emb_j + (size_t)b * DIM);
    float2 xi = ri[t], xj = rj[t];
    float si = xi.x * xi.x + xi.y * xi.y;
    float sj = xj.x * xj.x + xj.y * xj.y;
    #pragma unroll
    for (int o = 32; o > 0; o >>= 1) { si += __shfl_down(si, o, 64); sj += __shfl_down(sj, o, 64); }
    int lane = t & 63, w = t >> 6;
    if (lane == 0) { sc[0][w] = si; sc[1][w] = sj; }
    __syncthreads();
    float ni2 = sc[0][0] + sc[0][1] + sc[0][2] + sc[0][3];
    float nj2 = sc[1][0] + sc[1][1] + sc[1][2] + sc[1][3];
    float rni = 1.0f / fmaxf(sqrtf(ni2), 1e-12f);
    float rnj = 1.0f / fmaxf(sqrtf(nj2), 1e-12f);
    float zix = xi.x * rni, ziy = xi.y * rni;
    float zjx = xj.x * rnj, zjy = xj.y * rnj;
    // pack 2 floats -> 2 OCP e4m3 bytes (HW cvt, gfx950)
    int pki = __builtin_amdgcn_cvt_pk_fp8_f32(zix, ziy, 0, false);
    int pkj = __builtin_amdgcn_cvt_pk_fp8_f32(zjx, zjy, 0, false);
    ((unsigned short*)(reps + (size_t)b * DIM))[t]            = (unsigned short)pki;
    ((unsigned short*)(reps + (size_t)(b + B_SIZE) * DIM))[t] = (unsigned short)pkj;
    float d = zix * zjx + ziy * zjy;
    #pragma unroll
    for (int o = 32; o > 0; o >>= 1) d += __shfl_down(d, o, 64);
    if (lane == 0) sc[2][w] = d;
    __syncthreads();
    if (t == 0) pos[b] = sc[2][0] + sc[2][1] + sc[2][2] + sc[2][3];
}

// ---------- kernel 2: symmetric fused R*R^T (fp8 MFMA) + masked exp row/col sums ----------
// 256x128 tile, 8 waves (4 row-strips x 2 col-strips), each wave 64x64 (verified round-0
// wave shape: acc[4][4], 64 AGPR). 32 MFMAs per barrier-pair per wave (2x round-3 density).
// Blocks (I,J): 256-row group I, 128-col tile J, J >= 2I; even-diag (J==2I) lower half is
// a below-diagonal duplicate -> computed but suppressed at epilogue writes.
// fp8 LDS tiles: row r = 4 pieces of 16 B, piece p stored at p ^ ((r^(r>>2))&3).
// 2-buffer / 2-barrier pipeline (verified), counted vmcnt(3), 2 tiles in flight.
// Epilogue: atomic-free part[64][8192]; slot part[x][y in tile g]: g<=x row-side of
// (g>>1,x); g>x col-side of (x>>1,g). Each written exactly once.
#define BK 64
#define KITERS 8             // DIM / BK

__global__ __launch_bounds__(512) void sim_denom_kernel(
    const unsigned char* __restrict__ reps,
    const int* __restrict__ target,
    float* __restrict__ part)
{
    __shared__ __align__(16) unsigned char As0[256 * BK];
    __shared__ __align__(16) unsigned char As1[256 * BK];
    __shared__ __align__(16) unsigned char Bs0[128 * BK];
    __shared__ __align__(16) unsigned char Bs1[128 * BK];

    int t = threadIdx.x;
    // XCD-chunked remap: contiguous 132-run per XCD (1056 = 8*132, bijective).
    int id0 = blockIdx.x;
    int id = (id0 & 7) * 132 + (id0 >> 3);

    // --- band decode: 8x16 (I,J) supertile bands over the J>=2I region ---
    const int bA[10]   = {0,0,0,0,1,1,1,2,2,3};
    const int bB[10]   = {0,1,2,3,1,2,3,2,3,3};
    const int boff[11] = {0,72,200,328,456,528,656,784,856,984,1056};
    int s = 0;
    while (boff[s + 1] <= id) s++;
    int l = id - boff[s];
    int I, J;
    if (bA[s] == bB[s]) {                 // triangular band: start(r) = r*(17-r)
        int r = 0;
        while ((r + 1) * (16 - r) <= l) r++;
        I = bA[s] * 8 + r;
        J = bB[s] * 16 + 2 * r + (l - r * (17 - r));
    } else { I = bA[s] * 8 + (l >> 4); J = bB[s] * 16 + (l & 15); }

    int brow = I * 256;
    int bcol = J * 128;

    int wave = t >> 6, lane = t & 63;
    int wr = wave >> 1, wc = wave & 1;       // 4x2 waves, each 64x64 output
    int quad = lane >> 4, lm = lane & 15;

    f32x4 acc[4][4];
    #pragma unroll
    for (int i = 0; i < 4; i++)
        #pragma unroll
        for (int j = 0; j < 4; j++) acc[i][j] = (f32x4)0.0f;

    // staging: A: 2 calls, call c -> row c*128 + (t>>2), LDS byte t*16 + c*8192;
    // B: 1 call, row t>>2. swizzled source piece = (t&3) ^ ((row ^ (row>>2)) & 3)
    // (c*128 only flips row bit7 -> swz unaffected, shared between calls).
    int srow = t >> 2;
    int sp   = (t & 3) ^ ((srow ^ (srow >> 2)) & 3);
    const unsigned char* gA = reps + (size_t)(brow + srow) * DIM + sp * 16;
    const unsigned char* gB = reps + (size_t)(bcol + srow) * DIM + sp * 16;

    auto stage = [&](unsigned char* Ab, unsigned char* Bb, int k0) {
        async16(gA + k0, Ab + t * 16);
        async16(gA + k0 + 128 * DIM, Ab + t * 16 + 8192);
        async16(gB + k0, Bb + t * 16);
    };
    auto compute = [&](const unsigned char* Ab, const unsigned char* Bb) {
        #pragma unroll
        for (int ss = 0; ss < 2; ss++) {       // two K=32 sub-steps of BK=64
            long af[4], bf[4];
            #pragma unroll
            for (int mi = 0; mi < 4; mi++) {
                int rl = wr * 64 + mi * 16 + lm;           // 0..255
                int p = (ss * 2 + (quad >> 1)) ^ ((rl ^ (rl >> 2)) & 3);
                af[mi] = *(const long*)(Ab + rl * 64 + p * 16 + (quad & 1) * 8);
            }
            #pragma unroll
            for (int ni = 0; ni < 4; ni++) {
                int cl = wc * 64 + ni * 16 + lm;           // 0..127
                int p = (ss * 2 + (quad >> 1)) ^ ((cl ^ (cl >> 2)) & 3);
                bf[ni] = *(const long*)(Bb + cl * 64 + p * 16 + (quad & 1) * 8);
            }
            #pragma unroll
            for (int mi = 0; mi < 4; mi++)
                #pragma unroll
                for (int ni = 0; ni < 4; ni++)
                    acc[mi][ni] = __builtin_amdgcn_mfma_f32_16x16x32_fp8_fp8(
                        af[mi], bf[ni], acc[mi][ni], 0, 0, 0);
        }
    };

    // prologue: two tiles in flight (6 DMAs outstanding per thread)
    stage(As0, Bs0, 0);
    stage(As1, Bs1, BK);

    #pragma unroll
    for (int k = 0; k < KITERS; k++) {
        unsigned char* Ac = (k & 1) ? As1 : As0;
        unsigned char* Bc = (k & 1) ? Bs1 : Bs0;
        if (k < KITERS - 1) WAITVM(3); else WAITVM(0);   // drain loads(k), keep loads(k+1) in flight
        BARRIER();                         // all waves' loads(k) landed
        compute(Ac, Bc);
        BARRIER();                         // all waves done reading buf(k)
        if (k + 2 < KITERS) stage(Ac, Bc, (k + 2) * BK);
    }

    // ---------- epilogue: masked exp + row/col sums, atomic-free ----------
    // C/D layout: col=lane&15, row=quad*4+reg. Wave's rows all in one 128-half h.
    // Positives: global col-row = 4096 <=> (J - rtile)==32 at (rl&127)==cl.
    // LDS reuse: As0 = red_row[2 wc][256 rows], Bs0 = red_col[2 h][2 wr&1][128 cols]
    // (safe: last compute read of As0/Bs0 was k==6, fenced by k==7's barriers;
    //  k==7 compute reads As1/Bs1 only).
    int h = wr >> 1;
    int rtile = 2 * I + h;
    bool haspos = (J - rtile == 32);
    int labc[4];
    #pragma unroll
    for (int ni = 0; ni < 4; ni++)
        labc[ni] = target[(bcol + wc * 64 + ni * 16 + lm) & (B_SIZE - 1)];

    float* red_row = (float*)As0;    // [2][256] = 2 KB
    float* red_col = (float*)Bs0;    // [2][2][128] = 2 KB

    float colacc[4] = {0.f, 0.f, 0.f, 0.f};
    #pragma unroll
    for (int mi = 0; mi < 4; mi++) {
        #pragma unroll
        for (int r = 0; r < 4; r++) {
            int rl = wr * 64 + mi * 16 + quad * 4 + r;     // 0..255
            int labr = target[(brow + rl) & (B_SIZE - 1)];
            float rowacc = 0.0f;
            #pragma unroll
            for (int ni = 0; ni < 4; ni++) {
                int cl = wc * 64 + ni * 16 + lm;
                bool pospair = haspos && ((rl & 127) == cl);
                bool masked = (labr == labc[ni]) && !pospair;
                float e = masked ? 0.0f
                                 : __builtin_amdgcn_exp2f(acc[mi][ni][r] * EXP_SCALE);
                rowacc += e;
                colacc[ni] += e;
            }
            rowacc += __shfl_xor(rowacc, 1, 64);
            rowacc += __shfl_xor(rowacc, 2, 64);
            rowacc += __shfl_xor(rowacc, 4, 64);
            rowacc += __shfl_xor(rowacc, 8, 64);
            if (lm == 0) red_row[wc * 256 + rl] = rowacc;
        }
    }
    #pragma unroll
    for (int ni = 0; ni < 4; ni++) {
        float c = colacc[ni];
        c += __shfl_xor(c, 16, 64);
        c += __shfl_xor(c, 32, 64);
        if (quad == 0) red_col[h * 256 + (wr & 1) * 128 + wc * 64 + ni * 16 + lm] = c;
    }
    BARRIER();
    if (t < 256) {
        int th = t >> 7;                       // row-half of this output row
        if (2 * I + th <= J) {                 // suppress even-diag duplicate lower half
            float rs = red_row[t] + red_row[256 + t];
            part[(size_t)J * TWO_B + brow + t] = rs;
        }
    } else if (t < 512) {
        int c = t - 256;
        int ch = c >> 7, cc = c & 127;         // which row-half's col-sums
        int rt = 2 * I + ch;
        if (rt < J) {                          // skip diag (row-side covers) + duplicate half
            float cs = red_col[ch * 256 + cc] + red_col[ch * 256 + 128 + cc];
            part[(size_t)rt * TWO_B + bcol + cc] = cs;
        }
    }
}

// ---------- kernel 3: final loss (sum 64 part slices, then log/pos reduce) ----------
__global__ __launch_bounds__(256) void loss_kernel(
    const float* __restrict__ part, const float* __restrict__ pos,
    float* __restrict__ out)
{
    __shared__ float sc[4];
    int t = threadIdx.x, b = blockIdx.x;
    int i = b * 256 + t;
    float s = 0.0f;
    #pragma unroll
    for (int x = 0; x < 64; x++) s += part[(size_t)x * TWO_B + i];
    float v = logf(s + 1e-7f);                         // 32 blocks x 256 = 8192
    float p = (i < B_SIZE) ? pos[i] : 0.0f;
    // loss = (sum log(denom) - (2/t) * sum pos) / 2B ; 2/t = 4
    float v2 = v - 4.0f * p;
    #pragma unroll
    for (int o = 32; o > 0; o >>= 1) v2 += __shfl_down(v2, o, 64);
    int lane = t & 63, w = t >> 6;
    if (lane == 0) sc[w] = v2;
    __syncthreads();
    if (t == 0) atomicAdd(out, (sc[0] + sc[1] + sc[2] + sc[3]) * (1.0f / (float)TWO_B));
}

// ---------- launcher ----------
extern "C" void kernel_launch(void* const* d_in, const int* in_sizes, int n_in,
                              void* d_out, int out_size, void* d_ws, size_t ws_size,
                              hipStream_t stream)
{
    const float* emb_i  = (const float*)d_in[0];
    const float* emb_j  = (const float*)d_in[1];
    const int*   target = (const int*)d_in[2];
    float* out = (float*)d_out;

    char* ws = (char*)d_ws;
    unsigned char* reps = (unsigned char*)ws;                        // 8192*512 = 4 MB (fp8)
    float* pos   = (float*)(ws + (size_t)TWO_B * DIM);               // 16 KB
    float* part  = (float*)(ws + (size_t)TWO_B * DIM + B_SIZE * 4);  // 64*8192*4 = 2 MB

    norm_pos_kernel<<<B_SIZE, 256, 0, stream>>>(emb_i, emb_j, reps, pos, out);
    sim_denom_kernel<<<NBLK, 512, 0, stream>>>(reps, target, part);
    loss_kernel<<<TWO_B / 256, 256, 0, stream>>>(part, pos, out);
}

// Round 6
// 116.105 us; speedup vs baseline: 1.1340x; 1.1340x over previous
//
#include <hip/hip_runtime.h>
#include <hip/hip_bf16.h>
#include <cstdint>

#define B_SIZE 4096
#define TWO_B  8192
#define DIM    512           // row length; fp8 => 512 bytes per row
#define NBLK   1056          // blocks: (I,J), I in [0,32), J in [2I,64)
// exp(x/t) = exp2(x * log2(e)/t), t = 0.5
#define EXP_SCALE 2.8853900817779268f

typedef __attribute__((ext_vector_type(4))) float f32x4;

// raw waitcnt: vmcnt(n) with lgkmcnt/expcnt unconstrained (gfx9 encoding)
#define WAITVM(n) __builtin_amdgcn_s_waitcnt(0xF70 | (n))
#define BARRIER() __builtin_amdgcn_s_barrier()

// ---------- helpers ----------
__device__ __forceinline__ void async16(const void* g, void* l) {
    __builtin_amdgcn_global_load_lds(
        (const __attribute__((address_space(1))) unsigned int*)g,
        (__attribute__((address_space(3))) unsigned int*)l,
        16, 0, 0);
}

// ---------- kernel 1: L2-normalize rows -> fp8 reps, fp32 positives ----------
__global__ __launch_bounds__(256) void norm_pos_kernel(
    const float* __restrict__ emb_i, const float* __restrict__ emb_j,
    unsigned char* __restrict__ reps, float* __restrict__ pos,
    float* __restrict__ out)
{
    __shared__ float sc[3][4];
    int b = blockIdx.x, t = threadIdx.x;
    if (b == 0 && t == 0) out[0] = 0.0f;       // loss kernel accumulates atomically

    const float2* ri = (const float2*)(emb_i + (size_t)b * DIM);
    const float2* rj = (const float2*)(emb_j + (size_t)b * DIM);
    float2 xi = ri[t], xj = rj[t];
    float si = xi.x * xi.x + xi.y * xi.y;
    float sj = xj.x * xj.x + xj.y * xj.y;
    #pragma unroll
    for (int o = 32; o > 0; o >>= 1) { si += __shfl_down(si, o, 64); sj += __shfl_down(sj, o, 64); }
    int lane = t & 63, w = t >> 6;
    if (lane == 0) { sc[0][w] = si; sc[1][w] = sj; }
    __syncthreads();
    float ni2 = sc[0][0] + sc[0][1] + sc[0][2] + sc[0][3];
    float nj2 = sc[1][0] + sc[1][1] + sc[1][2] + sc[1][3];
    float rni = 1.0f / fmaxf(sqrtf(ni2), 1e-12f);
    float rnj = 1.0f / fmaxf(sqrtf(nj2), 1e-12f);
    float zix = xi.x * rni, ziy = xi.y * rni;
    float zjx = xj.x * rnj, zjy = xj.y * rnj;
    // pack 2 floats -> 2 OCP e4m3 bytes (HW cvt, gfx950)
    int pki = __builtin_amdgcn_cvt_pk_fp8_f32(zix, ziy, 0, false);
    int pkj = __builtin_amdgcn_cvt_pk_fp8_f32(zjx, zjy, 0, false);
    ((unsigned short*)(reps + (size_t)b * DIM))[t]            = (unsigned short)pki;
    ((unsigned short*)(reps + (size_t)(b + B_SIZE) * DIM))[t] = (unsigned short)pkj;
    float d = zix * zjx + ziy * zjy;
    #pragma unroll
    for (int o = 32; o > 0; o >>= 1) d += __shfl_down(d, o, 64);
    if (lane == 0) sc[2][w] = d;
    __syncthreads();
    if (t == 0) pos[b] = sc[2][0] + sc[2][1] + sc[2][2] + sc[2][3];
}

// ---------- kernel 2: symmetric fused R*R^T (fp8 MFMA) + masked exp row/col sums ----------
// 256x128 tile, 8 waves (4 row-strips x 2 col-strips), each wave 64x64 (verified round-0
// wave shape: acc[4][4], 64 AGPR). 32 MFMAs per barrier-pair per wave.
// __launch_bounds__(512, 4): force <=128 unified regs/wave (64 VGPR + 64 AGPR) so TWO
// 8-wave blocks fit per CU (round-5 at 132 regs fit only one -> occupancy 16.6%).
// Blocks (I,J): 256-row group I, 128-col tile J, J >= 2I; even-diag (J==2I) lower half is
// a below-diagonal duplicate -> computed but suppressed at epilogue writes.
// fp8 LDS tiles: row r = 4 pieces of 16 B, piece p stored at p ^ ((r^(r>>2))&3).
// 2-buffer / 2-barrier pipeline (verified), counted vmcnt(3), 2 tiles in flight.
// Epilogue: atomic-free part[64][8192]; slot part[x][y in tile g]: g<=x row-side of
// (g>>1,x); g>x col-side of (x>>1,g). Each written exactly once.
#define BK 64
#define KITERS 8             // DIM / BK

__global__ __launch_bounds__(512, 4) void sim_denom_kernel(
    const unsigned char* __restrict__ reps,
    const int* __restrict__ target,
    float* __restrict__ part)
{
    __shared__ __align__(16) unsigned char As0[256 * BK];
    __shared__ __align__(16) unsigned char As1[256 * BK];
    __shared__ __align__(16) unsigned char Bs0[128 * BK];
    __shared__ __align__(16) unsigned char Bs1[128 * BK];

    int t = threadIdx.x;
    // XCD-chunked remap: contiguous 132-run per XCD (1056 = 8*132, bijective).
    int id0 = blockIdx.x;
    int id = (id0 & 7) * 132 + (id0 >> 3);

    // --- band decode: 8x16 (I,J) supertile bands over the J>=2I region ---
    const int bA[10]   = {0,0,0,0,1,1,1,2,2,3};
    const int bB[10]   = {0,1,2,3,1,2,3,2,3,3};
    const int boff[11] = {0,72,200,328,456,528,656,784,856,984,1056};
    int s = 0;
    while (boff[s + 1] <= id) s++;
    int l = id - boff[s];
    int I, J;
    if (bA[s] == bB[s]) {                 // triangular band: start(r) = r*(17-r)
        int r = 0;
        while ((r + 1) * (16 - r) <= l) r++;
        I = bA[s] * 8 + r;
        J = bB[s] * 16 + 2 * r + (l - r * (17 - r));
    } else { I = bA[s] * 8 + (l >> 4); J = bB[s] * 16 + (l & 15); }

    int brow = I * 256;
    int bcol = J * 128;

    int wave = t >> 6, lane = t & 63;
    int wr = wave >> 1, wc = wave & 1;       // 4x2 waves, each 64x64 output
    int quad = lane >> 4, lm = lane & 15;

    f32x4 acc[4][4];
    #pragma unroll
    for (int i = 0; i < 4; i++)
        #pragma unroll
        for (int j = 0; j < 4; j++) acc[i][j] = (f32x4)0.0f;

    // staging: A: 2 calls, call c -> row c*128 + (t>>2), LDS byte t*16 + c*8192;
    // B: 1 call, row t>>2. swizzled source piece = (t&3) ^ ((row ^ (row>>2)) & 3)
    // (c*128 only flips row bit7 -> swz unaffected, shared between calls).
    int srow = t >> 2;
    int sp   = (t & 3) ^ ((srow ^ (srow >> 2)) & 3);
    const unsigned char* gA = reps + (size_t)(brow + srow) * DIM + sp * 16;
    const unsigned char* gB = reps + (size_t)(bcol + srow) * DIM + sp * 16;

    auto stage = [&](unsigned char* Ab, unsigned char* Bb, int k0) {
        async16(gA + k0, Ab + t * 16);
        async16(gA + k0 + 128 * DIM, Ab + t * 16 + 8192);
        async16(gB + k0, Bb + t * 16);
    };
    auto compute = [&](const unsigned char* Ab, const unsigned char* Bb) {
        #pragma unroll
        for (int ss = 0; ss < 2; ss++) {       // two K=32 sub-steps of BK=64
            long af[4], bf[4];
            #pragma unroll
            for (int mi = 0; mi < 4; mi++) {
                int rl = wr * 64 + mi * 16 + lm;           // 0..255
                int p = (ss * 2 + (quad >> 1)) ^ ((rl ^ (rl >> 2)) & 3);
                af[mi] = *(const long*)(Ab + rl * 64 + p * 16 + (quad & 1) * 8);
            }
            #pragma unroll
            for (int ni = 0; ni < 4; ni++) {
                int cl = wc * 64 + ni * 16 + lm;           // 0..127
                int p = (ss * 2 + (quad >> 1)) ^ ((cl ^ (cl >> 2)) & 3);
                bf[ni] = *(const long*)(Bb + cl * 64 + p * 16 + (quad & 1) * 8);
            }
            #pragma unroll
            for (int mi = 0; mi < 4; mi++)
                #pragma unroll
                for (int ni = 0; ni < 4; ni++)
                    acc[mi][ni] = __builtin_amdgcn_mfma_f32_16x16x32_fp8_fp8(
                        af[mi], bf[ni], acc[mi][ni], 0, 0, 0);
        }
    };

    // prologue: two tiles in flight (6 DMAs outstanding per thread)
    stage(As0, Bs0, 0);
    stage(As1, Bs1, BK);

    #pragma unroll
    for (int k = 0; k < KITERS; k++) {
        unsigned char* Ac = (k & 1) ? As1 : As0;
        unsigned char* Bc = (k & 1) ? Bs1 : Bs0;
        if (k < KITERS - 1) WAITVM(3); else WAITVM(0);   // drain loads(k), keep loads(k+1) in flight
        BARRIER();                         // all waves' loads(k) landed
        compute(Ac, Bc);
        BARRIER();                         // all waves done reading buf(k)
        if (k + 2 < KITERS) stage(Ac, Bc, (k + 2) * BK);
    }

    // ---------- epilogue: masked exp + row/col sums, atomic-free ----------
    // C/D layout: col=lane&15, row=quad*4+reg. Wave's rows all in one 128-half h.
    // Positives: global col-row = 4096 <=> (J - rtile)==32 at (rl&127)==cl.
    // LDS reuse: As0 = red_row[2 wc][256 rows], Bs0 = red_col[2 h][2 wr&1][128 cols]
    // (safe: last compute read of As0/Bs0 was k==6, fenced by k==7's barriers;
    //  k==7 compute reads As1/Bs1 only).
    int h = wr >> 1;
    int rtile = 2 * I + h;
    bool haspos = (J - rtile == 32);
    int labc[4];
    #pragma unroll
    for (int ni = 0; ni < 4; ni++)
        labc[ni] = target[(bcol + wc * 64 + ni * 16 + lm) & (B_SIZE - 1)];

    float* red_row = (float*)As0;    // [2][256] = 2 KB
    float* red_col = (float*)Bs0;    // [2][2][128] = 2 KB

    float colacc[4] = {0.f, 0.f, 0.f, 0.f};
    #pragma unroll
    for (int mi = 0; mi < 4; mi++) {
        #pragma unroll
        for (int r = 0; r < 4; r++) {
            int rl = wr * 64 + mi * 16 + quad * 4 + r;     // 0..255
            int labr = target[(brow + rl) & (B_SIZE - 1)];
            float rowacc = 0.0f;
            #pragma unroll
            for (int ni = 0; ni < 4; ni++) {
                int cl = wc * 64 + ni * 16 + lm;
                bool pospair = haspos && ((rl & 127) == cl);
                bool masked = (labr == labc[ni]) && !pospair;
                float e = masked ? 0.0f
                                 : __builtin_amdgcn_exp2f(acc[mi][ni][r] * EXP_SCALE);
                rowacc += e;
                colacc[ni] += e;
            }
            rowacc += __shfl_xor(rowacc, 1, 64);
            rowacc += __shfl_xor(rowacc, 2, 64);
            rowacc += __shfl_xor(rowacc, 4, 64);
            rowacc += __shfl_xor(rowacc, 8, 64);
            if (lm == 0) red_row[wc * 256 + rl] = rowacc;
        }
    }
    #pragma unroll
    for (int ni = 0; ni < 4; ni++) {
        float c = colacc[ni];
        c += __shfl_xor(c, 16, 64);
        c += __shfl_xor(c, 32, 64);
        if (quad == 0) red_col[h * 256 + (wr & 1) * 128 + wc * 64 + ni * 16 + lm] = c;
    }
    BARRIER();
    if (t < 256) {
        int th = t >> 7;                       // row-half of this output row
        if (2 * I + th <= J) {                 // suppress even-diag duplicate lower half
            float rs = red_row[t] + red_row[256 + t];
            part[(size_t)J * TWO_B + brow + t] = rs;
        }
    } else if (t < 512) {
        int c = t - 256;
        int ch = c >> 7, cc = c & 127;         // which row-half's col-sums
        int rt = 2 * I + ch;
        if (rt < J) {                          // skip diag (row-side covers) + duplicate half
            float cs = red_col[ch * 256 + cc] + red_col[ch * 256 + 128 + cc];
            part[(size_t)rt * TWO_B + bcol + cc] = cs;
        }
    }
}

// ---------- kernel 3: final loss (sum 64 part slices, then log/pos reduce) ----------
__global__ __launch_bounds__(256) void loss_kernel(
    const float* __restrict__ part, const float* __restrict__ pos,
    float* __restrict__ out)
{
    __shared__ float sc[4];
    int t = threadIdx.x, b = blockIdx.x;
    int i = b * 256 + t;
    float s = 0.0f;
    #pragma unroll
    for (int x = 0; x < 64; x++) s += part[(size_t)x * TWO_B + i];
    float v = logf(s + 1e-7f);                         // 32 blocks x 256 = 8192
    float p = (i < B_SIZE) ? pos[i] : 0.0f;
    // loss = (sum log(denom) - (2/t) * sum pos) / 2B ; 2/t = 4
    float v2 = v - 4.0f * p;
    #pragma unroll
    for (int o = 32; o > 0; o >>= 1) v2 += __shfl_down(v2, o, 64);
    int lane = t & 63, w = t >> 6;
    if (lane == 0) sc[w] = v2;
    __syncthreads();
    if (t == 0) atomicAdd(out, (sc[0] + sc[1] + sc[2] + sc[3]) * (1.0f / (float)TWO_B));
}

// ---------- launcher ----------
extern "C" void kernel_launch(void* const* d_in, const int* in_sizes, int n_in,
                              void* d_out, int out_size, void* d_ws, size_t ws_size,
                              hipStream_t stream)
{
    const float* emb_i  = (const float*)d_in[0];
    const float* emb_j  = (const float*)d_in[1];
    const int*   target = (const int*)d_in[2];
    float* out = (float*)d_out;

    char* ws = (char*)d_ws;
    unsigned char* reps = (unsigned char*)ws;                        // 8192*512 = 4 MB (fp8)
    float* pos   = (float*)(ws + (size_t)TWO_B * DIM);               // 16 KB
    float* part  = (float*)(ws + (size_t)TWO_B * DIM + B_SIZE * 4);  // 64*8192*4 = 2 MB

    norm_pos_kernel<<<B_SIZE, 256, 0, stream>>>(emb_i, emb_j, reps, pos, out);
    sim_denom_kernel<<<NBLK, 512, 0, stream>>>(reps, target, part);
    loss_kernel<<<TWO_B / 256, 256, 0, stream>>>(part, pos, out);
}

// Round 7
// 114.714 us; speedup vs baseline: 1.1478x; 1.0121x over previous
//
#include <hip/hip_runtime.h>
#include <hip/hip_bf16.h>
#include <cstdint>

#define B_SIZE 4096
#define TWO_B  8192
#define DIM    512           // row length; fp8 => 512 bytes per row
#define NBLK   1056          // blocks: (I,J), I in [0,32), J in [2I,64)
// exp(x/t) = exp2(x * log2(e)/t), t = 0.5
#define EXP_SCALE 2.8853900817779268f

typedef __attribute__((ext_vector_type(4))) float f32x4;

// raw waitcnt: vmcnt(n) with lgkmcnt/expcnt unconstrained (gfx9 encoding)
#define WAITVM(n) __builtin_amdgcn_s_waitcnt(0xF70 | (n))
#define BARRIER() __builtin_amdgcn_s_barrier()

// ---------- helpers ----------
__device__ __forceinline__ void async16(const void* g, void* l) {
    __builtin_amdgcn_global_load_lds(
        (const __attribute__((address_space(1))) unsigned int*)g,
        (__attribute__((address_space(3))) unsigned int*)l,
        16, 0, 0);
}

// ---------- kernel 1: L2-normalize rows -> fp8 reps, fp32 positives ----------
__global__ __launch_bounds__(256) void norm_pos_kernel(
    const float* __restrict__ emb_i, const float* __restrict__ emb_j,
    unsigned char* __restrict__ reps, float* __restrict__ pos,
    float* __restrict__ out)
{
    __shared__ float sc[3][4];
    int b = blockIdx.x, t = threadIdx.x;
    if (b == 0 && t == 0) out[0] = 0.0f;       // loss kernel accumulates atomically

    const float2* ri = (const float2*)(emb_i + (size_t)b * DIM);
    const float2* rj = (const float2*)(emb_j + (size_t)b * DIM);
    float2 xi = ri[t], xj = rj[t];
    float si = xi.x * xi.x + xi.y * xi.y;
    float sj = xj.x * xj.x + xj.y * xj.y;
    #pragma unroll
    for (int o = 32; o > 0; o >>= 1) { si += __shfl_down(si, o, 64); sj += __shfl_down(sj, o, 64); }
    int lane = t & 63, w = t >> 6;
    if (lane == 0) { sc[0][w] = si; sc[1][w] = sj; }
    __syncthreads();
    float ni2 = sc[0][0] + sc[0][1] + sc[0][2] + sc[0][3];
    float nj2 = sc[1][0] + sc[1][1] + sc[1][2] + sc[1][3];
    float rni = 1.0f / fmaxf(sqrtf(ni2), 1e-12f);
    float rnj = 1.0f / fmaxf(sqrtf(nj2), 1e-12f);
    float zix = xi.x * rni, ziy = xi.y * rni;
    float zjx = xj.x * rnj, zjy = xj.y * rnj;
    // pack 2 floats -> 2 OCP e4m3 bytes (HW cvt, gfx950)
    int pki = __builtin_amdgcn_cvt_pk_fp8_f32(zix, ziy, 0, false);
    int pkj = __builtin_amdgcn_cvt_pk_fp8_f32(zjx, zjy, 0, false);
    ((unsigned short*)(reps + (size_t)b * DIM))[t]            = (unsigned short)pki;
    ((unsigned short*)(reps + (size_t)(b + B_SIZE) * DIM))[t] = (unsigned short)pkj;
    float d = zix * zjx + ziy * zjy;
    #pragma unroll
    for (int o = 32; o > 0; o >>= 1) d += __shfl_down(d, o, 64);
    if (lane == 0) sc[2][w] = d;
    __syncthreads();
    if (t == 0) pos[b] = sc[2][0] + sc[2][1] + sc[2][2] + sc[2][3];
}

// ---------- kernel 2: symmetric fused R*R^T (fp8 MFMA) + masked exp row/col sums ----------
// 256x128 tile, 8 waves (4 row-strips x 2 col-strips), each wave 64x64 (acc[4][4], 64 AGPR).
// __launch_bounds__(512, 4): <=128 unified regs/wave -> 2 blocks/CU (verified r6: occ 29.7%).
// ROUND 7: phase-split probe (T3-lite + T5). Per K-tile the 32-MFMA cluster is split at the
// ss boundary into two 16-MFMA clusters with a mid-barrier; each cluster wrapped in
// s_setprio(1/0); ss1 frag reads issue BEFORE the mid-barrier so each barrier window has
// {ds_read issue || MFMA} interleave (m196). vmcnt accounting identical to r6, moved to
// loop bottom (same position relative to the same barrier).
// fp8 LDS tiles: row r = 4 pieces of 16 B, piece p stored at p ^ ((r^(r>>2))&3).
// Epilogue: atomic-free part[64][8192]; slot part[x][y in tile g]: g<=x row-side of
// (g>>1,x); g>x col-side of (x>>1,g). Each written exactly once.
#define BK 64
#define KITERS 8             // DIM / BK

__global__ __launch_bounds__(512, 4) void sim_denom_kernel(
    const unsigned char* __restrict__ reps,
    const int* __restrict__ target,
    float* __restrict__ part)
{
    __shared__ __align__(16) unsigned char As0[256 * BK];
    __shared__ __align__(16) unsigned char As1[256 * BK];
    __shared__ __align__(16) unsigned char Bs0[128 * BK];
    __shared__ __align__(16) unsigned char Bs1[128 * BK];

    int t = threadIdx.x;
    // XCD-chunked remap: contiguous 132-run per XCD (1056 = 8*132, bijective).
    int id0 = blockIdx.x;
    int id = (id0 & 7) * 132 + (id0 >> 3);

    // --- band decode: 8x16 (I,J) supertile bands over the J>=2I region ---
    const int bA[10]   = {0,0,0,0,1,1,1,2,2,3};
    const int bB[10]   = {0,1,2,3,1,2,3,2,3,3};
    const int boff[11] = {0,72,200,328,456,528,656,784,856,984,1056};
    int s = 0;
    while (boff[s + 1] <= id) s++;
    int l = id - boff[s];
    int I, J;
    if (bA[s] == bB[s]) {                 // triangular band: start(r) = r*(17-r)
        int r = 0;
        while ((r + 1) * (16 - r) <= l) r++;
        I = bA[s] * 8 + r;
        J = bB[s] * 16 + 2 * r + (l - r * (17 - r));
    } else { I = bA[s] * 8 + (l >> 4); J = bB[s] * 16 + (l & 15); }

    int brow = I * 256;
    int bcol = J * 128;

    int wave = t >> 6, lane = t & 63;
    int wr = wave >> 1, wc = wave & 1;       // 4x2 waves, each 64x64 output
    int quad = lane >> 4, lm = lane & 15;

    f32x4 acc[4][4];
    #pragma unroll
    for (int i = 0; i < 4; i++)
        #pragma unroll
        for (int j = 0; j < 4; j++) acc[i][j] = (f32x4)0.0f;

    // staging: A: 2 calls, call c -> row c*128 + (t>>2), LDS byte t*16 + c*8192;
    // B: 1 call, row t>>2. swizzled source piece = (t&3) ^ ((row ^ (row>>2)) & 3)
    int srow = t >> 2;
    int sp   = (t & 3) ^ ((srow ^ (srow >> 2)) & 3);
    const unsigned char* gA = reps + (size_t)(brow + srow) * DIM + sp * 16;
    const unsigned char* gB = reps + (size_t)(bcol + srow) * DIM + sp * 16;

    auto stage = [&](unsigned char* Ab, unsigned char* Bb, int k0) {
        async16(gA + k0, Ab + t * 16);
        async16(gA + k0 + 128 * DIM, Ab + t * 16 + 8192);
        async16(gB + k0, Bb + t * 16);
    };
    auto readfrags = [&](const unsigned char* Ab, const unsigned char* Bb, int ss,
                         long af[4], long bf[4]) {
        #pragma unroll
        for (int mi = 0; mi < 4; mi++) {
            int rl = wr * 64 + mi * 16 + lm;           // 0..255
            int p = (ss * 2 + (quad >> 1)) ^ ((rl ^ (rl >> 2)) & 3);
            af[mi] = *(const long*)(Ab + rl * 64 + p * 16 + (quad & 1) * 8);
        }
        #pragma unroll
        for (int ni = 0; ni < 4; ni++) {
            int cl = wc * 64 + ni * 16 + lm;           // 0..127
            int p = (ss * 2 + (quad >> 1)) ^ ((cl ^ (cl >> 2)) & 3);
            bf[ni] = *(const long*)(Bb + cl * 64 + p * 16 + (quad & 1) * 8);
        }
    };
    auto mfma16 = [&](const long af[4], const long bf[4]) {
        __builtin_amdgcn_s_setprio(1);
        #pragma unroll
        for (int mi = 0; mi < 4; mi++)
            #pragma unroll
            for (int ni = 0; ni < 4; ni++)
                acc[mi][ni] = __builtin_amdgcn_mfma_f32_16x16x32_fp8_fp8(
                    af[mi], bf[ni], acc[mi][ni], 0, 0, 0);
        __builtin_amdgcn_s_setprio(0);
    };

    // prologue: two tiles in flight (6 DMAs outstanding per thread)
    stage(As0, Bs0, 0);
    stage(As1, Bs1, BK);
    WAITVM(3);                 // drain loads(0), keep loads(1) in flight
    BARRIER();                 // buf 0 valid for all waves

    #pragma unroll
    for (int k = 0; k < KITERS; k++) {
        unsigned char* Ac = (k & 1) ? As1 : As0;
        unsigned char* Bc = (k & 1) ? Bs1 : Bs0;
        long af0[4], bf0[4], af1[4], bf1[4];
        readfrags(Ac, Bc, 0, af0, bf0);
        mfma16(af0, bf0);                 // phase A: ss0 MFMAs (ss1 reads issue below/around)
        readfrags(Ac, Bc, 1, af1, bf1);   // in flight across the mid-barrier
        BARRIER();                        // mid: phase boundary (role-split for setprio)
        mfma16(af1, bf1);                 // phase B: ss1 MFMAs (compiler lgkm-drains reads)
        BARRIER();                        // end: all waves consumed buf(k)
        if (k + 2 < KITERS) stage(Ac, Bc, (k + 2) * BK);
        if (k < KITERS - 2) WAITVM(3);    // drain loads(k+1), keep loads(k+2)
        else if (k == KITERS - 2) WAITVM(0);   // no loads(9): drain loads(7)
        if (k < KITERS - 1) BARRIER();    // top: buf(k+1) valid for next iter's reads
    }

    // ---------- epilogue: masked exp + row/col sums, atomic-free ----------
    // C/D layout: col=lane&15, row=quad*4+reg. Wave's rows all in one 128-half h.
    // Positives: global col-row = 4096 <=> (J - rtile)==32 at (rl&127)==cl.
    // LDS reuse: As0/Bs0 (last read k==6; drained before k==6 end-barrier; k==7 reads As1/Bs1).
    int h = wr >> 1;
    int rtile = 2 * I + h;
    bool haspos = (J - rtile == 32);
    int labc[4];
    #pragma unroll
    for (int ni = 0; ni < 4; ni++)
        labc[ni] = target[(bcol + wc * 64 + ni * 16 + lm) & (B_SIZE - 1)];

    float* red_row = (float*)As0;    // [2][256] = 2 KB
    float* red_col = (float*)Bs0;    // [2][2][128] = 2 KB

    float colacc[4] = {0.f, 0.f, 0.f, 0.f};
    #pragma unroll
    for (int mi = 0; mi < 4; mi++) {
        #pragma unroll
        for (int r = 0; r < 4; r++) {
            int rl = wr * 64 + mi * 16 + quad * 4 + r;     // 0..255
            int labr = target[(brow + rl) & (B_SIZE - 1)];
            float rowacc = 0.0f;
            #pragma unroll
            for (int ni = 0; ni < 4; ni++) {
                int cl = wc * 64 + ni * 16 + lm;
                bool pospair = haspos && ((rl & 127) == cl);
                bool masked = (labr == labc[ni]) && !pospair;
                float e = masked ? 0.0f
                                 : __builtin_amdgcn_exp2f(acc[mi][ni][r] * EXP_SCALE);
                rowacc += e;
                colacc[ni] += e;
            }
            rowacc += __shfl_xor(rowacc, 1, 64);
            rowacc += __shfl_xor(rowacc, 2, 64);
            rowacc += __shfl_xor(rowacc, 4, 64);
            rowacc += __shfl_xor(rowacc, 8, 64);
            if (lm == 0) red_row[wc * 256 + rl] = rowacc;
        }
    }
    #pragma unroll
    for (int ni = 0; ni < 4; ni++) {
        float c = colacc[ni];
        c += __shfl_xor(c, 16, 64);
        c += __shfl_xor(c, 32, 64);
        if (quad == 0) red_col[h * 256 + (wr & 1) * 128 + wc * 64 + ni * 16 + lm] = c;
    }
    BARRIER();
    if (t < 256) {
        int th = t >> 7;                       // row-half of this output row
        if (2 * I + th <= J) {                 // suppress even-diag duplicate lower half
            float rs = red_row[t] + red_row[256 + t];
            part[(size_t)J * TWO_B + brow + t] = rs;
        }
    } else if (t < 512) {
        int c = t - 256;
        int ch = c >> 7, cc = c & 127;         // which row-half's col-sums
        int rt = 2 * I + ch;
        if (rt < J) {                          // skip diag (row-side covers) + duplicate half
            float cs = red_col[ch * 256 + cc] + red_col[ch * 256 + 128 + cc];
            part[(size_t)rt * TWO_B + bcol + cc] = cs;
        }
    }
}

// ---------- kernel 3: final loss (sum 64 part slices, then log/pos reduce) ----------
__global__ __launch_bounds__(256) void loss_kernel(
    const float* __restrict__ part, const float* __restrict__ pos,
    float* __restrict__ out)
{
    __shared__ float sc[4];
    int t = threadIdx.x, b = blockIdx.x;
    int i = b * 256 + t;
    float s = 0.0f;
    #pragma unroll
    for (int x = 0; x < 64; x++) s += part[(size_t)x * TWO_B + i];
    float v = logf(s + 1e-7f);                         // 32 blocks x 256 = 8192
    float p = (i < B_SIZE) ? pos[i] : 0.0f;
    // loss = (sum log(denom) - (2/t) * sum pos) / 2B ; 2/t = 4
    float v2 = v - 4.0f * p;
    #pragma unroll
    for (int o = 32; o > 0; o >>= 1) v2 += __shfl_down(v2, o, 64);
    int lane = t & 63, w = t >> 6;
    if (lane == 0) sc[w] = v2;
    __syncthreads();
    if (t == 0) atomicAdd(out, (sc[0] + sc[1] + sc[2] + sc[3]) * (1.0f / (float)TWO_B));
}

// ---------- launcher ----------
extern "C" void kernel_launch(void* const* d_in, const int* in_sizes, int n_in,
                              void* d_out, int out_size, void* d_ws, size_t ws_size,
                              hipStream_t stream)
{
    const float* emb_i  = (const float*)d_in[0];
    const float* emb_j  = (const float*)d_in[1];
    const int*   target = (const int*)d_in[2];
    float* out = (float*)d_out;

    char* ws = (char*)d_ws;
    unsigned char* reps = (unsigned char*)ws;                        // 8192*512 = 4 MB (fp8)
    float* pos   = (float*)(ws + (size_t)TWO_B * DIM);               // 16 KB
    float* part  = (float*)(ws + (size_t)TWO_B * DIM + B_SIZE * 4);  // 64*8192*4 = 2 MB

    norm_pos_kernel<<<B_SIZE, 256, 0, stream>>>(emb_i, emb_j, reps, pos, out);
    sim_denom_kernel<<<NBLK, 512, 0, stream>>>(reps, target, part);
    loss_kernel<<<TWO_B / 256, 256, 0, stream>>>(part, pos, out);
}